// Round 6
// baseline (160.349 us; speedup 1.0000x reference)
//
#include <hip/hip_runtime.h>

// Attention S=8192 D=256, scale=1/sqrt(8192)(seq len). Round 6:
//  - S^T trick: compute S^T = K*Q^T (swap MFMA operands). C-layout then holds
//    P[q=l15][key=qq*4+r] per lane == A-frag layout of mfma_f32_16x16x16f16
//    (K=16: k=qq*4+j). P never touches LDS: exp2 -> cvt_f16 -> PV MFMA.
//  - PV + V in f16 (more mantissa than bf16; V tiled-transposed as before)
//  - double-buffered K/V LDS, ONE barrier/iter (lgkmcnt drains at s_barrier
//    make single-barrier dbuf safe)
//  - all LDS reads/writes at bank floor by construction (kf/vf b64, stg b128)
// QK stays fp8 e4m3 (R5-verified, absmax 4.9e-4 of 8.2e-4 budget).

typedef __attribute__((ext_vector_type(4))) float    f32x4;
typedef __attribute__((ext_vector_type(4))) int      i32x4;
typedef __attribute__((ext_vector_type(4))) _Float16 h4;
typedef __attribute__((ext_vector_type(8))) _Float16 h8;
typedef long __attribute__((may_alias)) long_a;
typedef i32x4 __attribute__((may_alias)) i32x4_a;
typedef h4    __attribute__((may_alias)) h4_a;
typedef h8    __attribute__((may_alias)) h8_a;

#define SEQ 8192
#define DIM 256
#define NSPLIT 8
#define KPS (SEQ / NSPLIT)          // 1024 keys per split
#define BN 32                        // keys per iteration
#define ITERS (KPS / BN)             // 32
#define BM 128                       // q rows per block = 4 waves x 32

#define KSC (1.4426950408889634f / 90.50966799187808f)   // log2(e)/sqrt(8192)

// ---- fused prep: Q,K fp32->fp8 e4m3 row-major; V -> f16 Vt[kt][d][32k] ----
__global__ void __launch_bounds__(256)
prep(const float* __restrict__ Q, const float* __restrict__ K,
     const float* __restrict__ V, unsigned char* __restrict__ Q8,
     unsigned char* __restrict__ K8, _Float16* __restrict__ Vt) {
    __shared__ _Float16 tile[32][264];
    int b = blockIdx.x, t = threadIdx.x;

    // Q/K -> fp8 (HW RNE): block b = rows b*32..+31; thread: row t>>3, 32 cols
    {
        int row = b * 32 + (t >> 3);
        int c0 = (t & 7) * 8;
        const f32x4* q4 = (const f32x4*)Q + (size_t)row * 64 + c0;
        const f32x4* k4 = (const f32x4*)K + (size_t)row * 64 + c0;
        int qo[8], ko[8];
        #pragma unroll
        for (int i = 0; i < 8; ++i) {
            f32x4 q = q4[i], k = k4[i];
            int dq = 0, dk = 0;
            dq = __builtin_amdgcn_cvt_pk_fp8_f32(q.x, q.y, dq, false);
            dq = __builtin_amdgcn_cvt_pk_fp8_f32(q.z, q.w, dq, true);
            dk = __builtin_amdgcn_cvt_pk_fp8_f32(k.x, k.y, dk, false);
            dk = __builtin_amdgcn_cvt_pk_fp8_f32(k.z, k.w, dk, true);
            qo[i] = dq; ko[i] = dk;
        }
        i32x4* qd = (i32x4*)(Q8 + (size_t)row * 256 + (t & 7) * 32);
        i32x4* kd = (i32x4*)(K8 + (size_t)row * 256 + (t & 7) * 32);
        qd[0] = *(i32x4*)&qo[0]; qd[1] = *(i32x4*)&qo[4];
        kd[0] = *(i32x4*)&ko[0]; kd[1] = *(i32x4*)&ko[4];
    }

    // V tile b (keys b*32..+31) -> Vt[b][d][k], f16
    #pragma unroll
    for (int i = 0; i < 8; ++i) {
        int c = t + i * 256;
        int row = c >> 6, col = c & 63;
        f32x4 v = ((const f32x4*)V)[(size_t)(b * 32 + row) * 64 + col];
        tile[row][col * 4 + 0] = (_Float16)v.x;
        tile[row][col * 4 + 1] = (_Float16)v.y;
        tile[row][col * 4 + 2] = (_Float16)v.z;
        tile[row][col * 4 + 3] = (_Float16)v.w;
    }
    __syncthreads();
    _Float16* dst = Vt + (size_t)b * 8192 + t * 32;
    #pragma unroll
    for (int k8 = 0; k8 < 4; ++k8) {
        h8 w;
        #pragma unroll
        for (int j = 0; j < 8; ++j) w[j] = tile[k8 * 8 + j][t];
        *(h8*)(dst + k8 * 8) = w;
    }
}

// ---------------- main attention kernel ----------------------------------
// grid = 64 q-tiles x 8 splits, 256 threads (4 waves x 32 rows).
__global__ void __launch_bounds__(256, 2)
attn(const unsigned char* __restrict__ Q8, const unsigned char* __restrict__ K8,
     const _Float16* __restrict__ Vt, _Float16* __restrict__ Op,
     float* __restrict__ lp) {
    __shared__ unsigned char K_lds[2][32][272];   // fp8; stride 272B: b64 reads at floor
    __shared__ _Float16 V_lds[2][256][40];        // f16; stride 40h: b64 reads at floor

    int tid = threadIdx.x;
    int wid = tid >> 6, lane = tid & 63;
    int l15 = lane & 15, qq = lane >> 4;
    int qt_blk = blockIdx.x >> 3, sp = blockIdx.x & 7;
    int qrow0 = qt_blk * BM + wid * 32;

    // Q fp8 B-frags (S^T: B[n=q=l15][k=s*32+qq*8+j]), held in regs all kernel
    long qf[2][8];
    #pragma unroll
    for (int t = 0; t < 2; ++t) {
        const unsigned char* p = Q8 + (size_t)(qrow0 + t * 16 + l15) * DIM + qq * 8;
        #pragma unroll
        for (int s = 0; s < 8; ++s) qf[t][s] = *(const long_a*)(p + s * 32);
    }

    // ones B-frag (f16, K=16) for l = P @ ones: B[n][k] = (n==0)
    _Float16 one = (l15 == 0) ? (_Float16)1.0f : (_Float16)0.0f;
    h4 of = {one, one, one, one};

    // staging: K fp8 8KB (2 b128/thread), V f16 16KB (4 b128/thread)
    const unsigned char* ksrc = K8 + (size_t)(sp * KPS + (tid >> 4)) * DIM + (tid & 15) * 16;
    const _Float16* vsrc = Vt + (size_t)sp * (KPS / BN) * 8192 + (tid >> 2) * 32 + (tid & 3) * 8;
    int kr = tid >> 4, kc = (tid & 15) * 16;
    int vr = tid >> 2, vc = (tid & 3) * 8;

    f32x4 acc[2][16] = {};
    f32x4 accl[2] = {};
    i32x4 kreg[2];
    h8 vreg[4];

    // prologue: stage tile 0 into buffer 0
    kreg[0] = *(const i32x4_a*)ksrc;
    kreg[1] = *(const i32x4_a*)(ksrc + 16 * DIM);
    #pragma unroll
    for (int p = 0; p < 4; ++p) vreg[p] = *(const h8_a*)(vsrc + p * 64 * 32);
    ksrc += BN * DIM; vsrc += 8192;
    *(i32x4_a*)&K_lds[0][kr][kc]      = kreg[0];
    *(i32x4_a*)&K_lds[0][kr + 16][kc] = kreg[1];
    #pragma unroll
    for (int p = 0; p < 4; ++p) *(h8_a*)&V_lds[0][vr + p * 64][vc] = vreg[p];
    __syncthreads();

    for (int it = 0; it < ITERS; ++it) {
        int b = it & 1;
        // prefetch tile it+1 into regs (global, L2-hot; overlaps compute)
        if (it + 1 < ITERS) {
            kreg[0] = *(const i32x4_a*)ksrc;
            kreg[1] = *(const i32x4_a*)(ksrc + 16 * DIM);
            #pragma unroll
            for (int p = 0; p < 4; ++p) vreg[p] = *(const h8_a*)(vsrc + p * 64 * 32);
            ksrc += BN * DIM; vsrc += 8192;
        }

        // S^T = K @ Q^T : fp8 16x16x32, A=K (m=key), B=Q (n=q)
        // sc[kt][qt]: lane holds S^T[key=qq*4+r][q=l15]
        f32x4 sc[2][2] = {};
        #pragma unroll
        for (int s = 0; s < 8; ++s) {
            long kf0 = *(const long_a*)&K_lds[b][l15][s * 32 + qq * 8];
            long kf1 = *(const long_a*)&K_lds[b][16 + l15][s * 32 + qq * 8];
            #pragma unroll
            for (int t = 0; t < 2; ++t) {
                sc[0][t] = __builtin_amdgcn_mfma_f32_16x16x32_fp8_fp8(kf0, qf[t][s], sc[0][t], 0, 0, 0);
                sc[1][t] = __builtin_amdgcn_mfma_f32_16x16x32_fp8_fp8(kf1, qf[t][s], sc[1][t], 0, 0, 0);
            }
        }

        // P = exp2(min(S*KSC,16)) straight into f16 A-frags for K=16 PV MFMA:
        // pfrag[kt][qt] = P[q=l15][k16=qq*4+j]  (no LDS round-trip)
        h4 pfrag[2][2];
        #pragma unroll
        for (int kt = 0; kt < 2; ++kt)
            #pragma unroll
            for (int t = 0; t < 2; ++t)
                #pragma unroll
                for (int r = 0; r < 4; ++r) {
                    float e = fminf(sc[kt][t][r] * KSC, 16.0f);
                    pfrag[kt][t][r] = (_Float16)__builtin_amdgcn_exp2f(e);
                }

        // O += P @ V : f16 16x16x16; vf b64 reads at bank floor
        #pragma unroll
        for (int n = 0; n < 16; ++n) {
            h4 vf0 = *(const h4_a*)&V_lds[b][n * 16 + l15][qq * 4];
            h4 vf1 = *(const h4_a*)&V_lds[b][n * 16 + l15][16 + qq * 4];
            acc[0][n] = __builtin_amdgcn_mfma_f32_16x16x16f16(pfrag[0][0], vf0, acc[0][n], 0, 0, 0);
            acc[0][n] = __builtin_amdgcn_mfma_f32_16x16x16f16(pfrag[1][0], vf1, acc[0][n], 0, 0, 0);
            acc[1][n] = __builtin_amdgcn_mfma_f32_16x16x16f16(pfrag[0][1], vf0, acc[1][n], 0, 0, 0);
            acc[1][n] = __builtin_amdgcn_mfma_f32_16x16x16f16(pfrag[1][1], vf1, acc[1][n], 0, 0, 0);
        }
        accl[0] = __builtin_amdgcn_mfma_f32_16x16x16f16(pfrag[0][0], of, accl[0], 0, 0, 0);
        accl[0] = __builtin_amdgcn_mfma_f32_16x16x16f16(pfrag[1][0], of, accl[0], 0, 0, 0);
        accl[1] = __builtin_amdgcn_mfma_f32_16x16x16f16(pfrag[0][1], of, accl[1], 0, 0, 0);
        accl[1] = __builtin_amdgcn_mfma_f32_16x16x16f16(pfrag[1][1], of, accl[1], 0, 0, 0);

        // write tile it+1 into the other buffer; one barrier per iter.
        // Safe: compiler drains lgkmcnt before s_barrier, so every wave's
        // iter-it reads of buf[b] complete before any wave's writes land there
        // next iteration.
        if (it + 1 < ITERS) {
            int nb = b ^ 1;
            *(i32x4_a*)&K_lds[nb][kr][kc]      = kreg[0];
            *(i32x4_a*)&K_lds[nb][kr + 16][kc] = kreg[1];
            #pragma unroll
            for (int p = 0; p < 4; ++p) *(h8_a*)&V_lds[nb][vr + p * 64][vc] = vreg[p];
            __syncthreads();
        }
    }

    // epilogue: f16 O partials + fp32 l partials
    #pragma unroll
    for (int t = 0; t < 2; ++t) {
        #pragma unroll
        for (int n = 0; n < 16; ++n)
            #pragma unroll
            for (int r = 0; r < 4; ++r) {
                int row = qrow0 + t * 16 + qq * 4 + r;
                Op[((size_t)sp * SEQ + row) * DIM + n * 16 + l15] = (_Float16)acc[t][n][r];
            }
        if (l15 == 0) {
            #pragma unroll
            for (int r = 0; r < 4; ++r)
                lp[(size_t)sp * SEQ + qrow0 + t * 16 + qq * 4 + r] = accl[t][r];
        }
    }
}

// ---------------- combine: out = sum_s(Op_s) / sum_s(lp_s) ----------------
__global__ void combine(const _Float16* __restrict__ Op, const float* __restrict__ lp,
                        float* __restrict__ out) {
    int idx = blockIdx.x * 256 + threadIdx.x;   // f32x4 chunk, 524288 total
    int row = idx >> 6;
    f32x4 a = {};
    float l = 0.0f;
    #pragma unroll
    for (int s = 0; s < NSPLIT; ++s) {
        h4 h = *(const h4*)(Op + (size_t)s * SEQ * DIM + (size_t)idx * 4);
        a.x += (float)h.x; a.y += (float)h.y; a.z += (float)h.z; a.w += (float)h.w;
        l += lp[s * SEQ + row];
    }
    float linv = 1.0f / (l + 1e-20f);
    ((f32x4*)out)[idx] = a * linv;
}

extern "C" void kernel_launch(void* const* d_in, const int* in_sizes, int n_in,
                              void* d_out, int out_size, void* d_ws, size_t ws_size,
                              hipStream_t stream) {
    const float* Q = (const float*)d_in[0];
    const float* K = (const float*)d_in[1];
    const float* V = (const float*)d_in[2];
    float* out = (float*)d_out;

    char* ws = (char*)d_ws;
    unsigned char* Q8 = (unsigned char*)ws;                // 2 MB fp8
    unsigned char* K8 = (unsigned char*)(ws + (2u << 20)); // 2 MB fp8
    _Float16* Vt = (_Float16*)(ws + (4u << 20));           // 4 MB f16 tiled-T
    _Float16* Op = (_Float16*)(ws + (8u << 20));           // 32 MB f16 partials
    float*    lp = (float*)(ws + (40u << 20));             // 256 KB

    prep   <<<256, 256, 0, stream>>>(Q, K, V, Q8, K8, Vt);
    attn   <<<NSPLIT * (SEQ / BM), 256, 0, stream>>>(Q8, K8, Vt, Op, lp);
    combine<<<2048, 256, 0, stream>>>(Op, lp, out);
}

// Round 7
// 143.252 us; speedup vs baseline: 1.1193x; 1.1193x over previous
//
#include <hip/hip_runtime.h>

// Attention S=8192 D=256, scale=1/sqrt(8192)(seq len). Round 7:
//  - pi-permutation trick: S^T C-layout gives lane qq keys {4qq..+3}u{16+4qq..+3};
//    K=32 A-frag wants {8qq..+7}. Relabel keys via pi(8a+j)=4a+j / 16+4a+j-4,
//    baked into the Vt prep transpose. exp2'd scores ARE the PV A-frag ->
//    PV back to mfma_f32_16x16x32_f16: 34 MFMAs/iter (was 68), 16 b128 vf
//    (was 32 b64). No P LDS, no cross-lane.
//  - rest identical to R6: fp8 S^T QK, dbuf K/V LDS, one barrier/iter
// Note: SQ_LDS_BANK_CONFLICT is floor-dominated for wide accesses (R5/R6
// static analysis at floor but counter ~1.4e7) -- not actionable.

typedef __attribute__((ext_vector_type(4))) float    f32x4;
typedef __attribute__((ext_vector_type(4))) int      i32x4;
typedef __attribute__((ext_vector_type(4))) _Float16 h4;
typedef __attribute__((ext_vector_type(8))) _Float16 h8;
typedef long __attribute__((may_alias)) long_a;
typedef i32x4 __attribute__((may_alias)) i32x4_a;
typedef h8    __attribute__((may_alias)) h8_a;

#define SEQ 8192
#define DIM 256
#define NSPLIT 8
#define KPS (SEQ / NSPLIT)          // 1024 keys per split
#define BN 32                        // keys per iteration
#define ITERS (KPS / BN)             // 32
#define BM 128                       // q rows per block = 4 waves x 32

#define KSC (1.4426950408889634f / 90.50966799187808f)   // log2(e)/sqrt(8192)

// ---- fused prep: Q,K fp32->fp8 e4m3 row-major; V -> f16 Vt[kt][d][pi(k)] ----
__global__ void __launch_bounds__(256)
prep(const float* __restrict__ Q, const float* __restrict__ K,
     const float* __restrict__ V, unsigned char* __restrict__ Q8,
     unsigned char* __restrict__ K8, _Float16* __restrict__ Vt) {
    __shared__ _Float16 tile[32][264];
    int b = blockIdx.x, t = threadIdx.x;

    // Q/K -> fp8 (HW RNE)
    {
        int row = b * 32 + (t >> 3);
        int c0 = (t & 7) * 8;
        const f32x4* q4 = (const f32x4*)Q + (size_t)row * 64 + c0;
        const f32x4* k4 = (const f32x4*)K + (size_t)row * 64 + c0;
        int qo[8], ko[8];
        #pragma unroll
        for (int i = 0; i < 8; ++i) {
            f32x4 q = q4[i], k = k4[i];
            int dq = 0, dk = 0;
            dq = __builtin_amdgcn_cvt_pk_fp8_f32(q.x, q.y, dq, false);
            dq = __builtin_amdgcn_cvt_pk_fp8_f32(q.z, q.w, dq, true);
            dk = __builtin_amdgcn_cvt_pk_fp8_f32(k.x, k.y, dk, false);
            dk = __builtin_amdgcn_cvt_pk_fp8_f32(k.z, k.w, dk, true);
            qo[i] = dq; ko[i] = dk;
        }
        i32x4* qd = (i32x4*)(Q8 + (size_t)row * 256 + (t & 7) * 32);
        i32x4* kd = (i32x4*)(K8 + (size_t)row * 256 + (t & 7) * 32);
        qd[0] = *(i32x4*)&qo[0]; qd[1] = *(i32x4*)&qo[4];
        kd[0] = *(i32x4*)&ko[0]; kd[1] = *(i32x4*)&ko[4];
    }

    // V tile b (physical keys b*32..+31) -> Vt[b][d][k_logical], f16,
    // logical slot 8a+j holds physical key pi(8a+j)= 4a+j (j<4) / 16+4a+j-4.
    #pragma unroll
    for (int i = 0; i < 8; ++i) {
        int c = t + i * 256;
        int row = c >> 6, col = c & 63;
        f32x4 v = ((const f32x4*)V)[(size_t)(b * 32 + row) * 64 + col];
        tile[row][col * 4 + 0] = (_Float16)v.x;
        tile[row][col * 4 + 1] = (_Float16)v.y;
        tile[row][col * 4 + 2] = (_Float16)v.z;
        tile[row][col * 4 + 3] = (_Float16)v.w;
    }
    __syncthreads();
    _Float16* dst = Vt + (size_t)b * 8192 + t * 32;
    #pragma unroll
    for (int a = 0; a < 4; ++a) {
        h8 w;
        #pragma unroll
        for (int j = 0; j < 4; ++j) {
            w[j]     = tile[4 * a + j][t];          // pi(8a+j), j<4
            w[4 + j] = tile[16 + 4 * a + j][t];     // pi(8a+4+j)
        }
        *(h8*)(dst + a * 8) = w;
    }
}

// ---------------- main attention kernel ----------------------------------
// grid = 64 q-tiles x 8 splits, 256 threads (4 waves x 32 rows).
__global__ void __launch_bounds__(256, 2)
attn(const unsigned char* __restrict__ Q8, const unsigned char* __restrict__ K8,
     const _Float16* __restrict__ Vt, _Float16* __restrict__ Op,
     float* __restrict__ lp) {
    __shared__ unsigned char K_lds[2][32][272];   // fp8; b64 reads at bank floor
    __shared__ _Float16 V_lds[2][256][40];        // f16; b128 reads at bank floor

    int tid = threadIdx.x;
    int wid = tid >> 6, lane = tid & 63;
    int l15 = lane & 15, qq = lane >> 4;
    int qt_blk = blockIdx.x >> 3, sp = blockIdx.x & 7;
    int qrow0 = qt_blk * BM + wid * 32;

    // Q fp8 B-frags (S^T: B[n=q=l15][k=s*32+qq*8+j])
    long qf[2][8];
    #pragma unroll
    for (int t = 0; t < 2; ++t) {
        const unsigned char* p = Q8 + (size_t)(qrow0 + t * 16 + l15) * DIM + qq * 8;
        #pragma unroll
        for (int s = 0; s < 8; ++s) qf[t][s] = *(const long_a*)(p + s * 32);
    }

    // ones B-frag (f16, K=32) for l = P @ ones: B[n][k] = (n==0)
    _Float16 one = (l15 == 0) ? (_Float16)1.0f : (_Float16)0.0f;
    h8 of = {one, one, one, one, one, one, one, one};

    // staging: K fp8 8KB (2 b128/thread), V f16 16KB (4 b128/thread)
    const unsigned char* ksrc = K8 + (size_t)(sp * KPS + (tid >> 4)) * DIM + (tid & 15) * 16;
    const _Float16* vsrc = Vt + (size_t)sp * (KPS / BN) * 8192 + (tid >> 2) * 32 + (tid & 3) * 8;
    int kr = tid >> 4, kc = (tid & 15) * 16;
    int vr = tid >> 2, vc = (tid & 3) * 8;

    f32x4 acc[2][16] = {};
    f32x4 accl[2] = {};
    i32x4 kreg[2];
    h8 vreg[4];

    // prologue: stage tile 0 into buffer 0
    kreg[0] = *(const i32x4_a*)ksrc;
    kreg[1] = *(const i32x4_a*)(ksrc + 16 * DIM);
    #pragma unroll
    for (int p = 0; p < 4; ++p) vreg[p] = *(const h8_a*)(vsrc + p * 64 * 32);
    ksrc += BN * DIM; vsrc += 8192;
    *(i32x4_a*)&K_lds[0][kr][kc]      = kreg[0];
    *(i32x4_a*)&K_lds[0][kr + 16][kc] = kreg[1];
    #pragma unroll
    for (int p = 0; p < 4; ++p) *(h8_a*)&V_lds[0][vr + p * 64][vc] = vreg[p];
    __syncthreads();

    for (int it = 0; it < ITERS; ++it) {
        int b = it & 1;
        // prefetch tile it+1 into regs (L2-hot; overlaps compute)
        if (it + 1 < ITERS) {
            kreg[0] = *(const i32x4_a*)ksrc;
            kreg[1] = *(const i32x4_a*)(ksrc + 16 * DIM);
            #pragma unroll
            for (int p = 0; p < 4; ++p) vreg[p] = *(const h8_a*)(vsrc + p * 64 * 32);
            ksrc += BN * DIM; vsrc += 8192;
        }

        // S^T = K @ Q^T : fp8 16x16x32; sc[kt][qt] lane holds
        // S^T[key = kt*16 + qq*4+r][q = l15]
        f32x4 sc[2][2] = {};
        #pragma unroll
        for (int s = 0; s < 8; ++s) {
            long kf0 = *(const long_a*)&K_lds[b][l15][s * 32 + qq * 8];
            long kf1 = *(const long_a*)&K_lds[b][16 + l15][s * 32 + qq * 8];
            #pragma unroll
            for (int t = 0; t < 2; ++t) {
                sc[0][t] = __builtin_amdgcn_mfma_f32_16x16x32_fp8_fp8(kf0, qf[t][s], sc[0][t], 0, 0, 0);
                sc[1][t] = __builtin_amdgcn_mfma_f32_16x16x32_fp8_fp8(kf1, qf[t][s], sc[1][t], 0, 0, 0);
            }
        }

        // P = exp2(min(S*KSC,16)): with the pi-permuted Vt, [sc0|sc1] IS the
        // K=32 A-frag (lane qq logical keys 8qq..8qq+7). No LDS, no shuffle.
        h8 pfrag[2];
        #pragma unroll
        for (int t = 0; t < 2; ++t)
            #pragma unroll
            for (int r = 0; r < 4; ++r) {
                pfrag[t][r]     = (_Float16)__builtin_amdgcn_exp2f(fminf(sc[0][t][r] * KSC, 16.0f));
                pfrag[t][4 + r] = (_Float16)__builtin_amdgcn_exp2f(fminf(sc[1][t][r] * KSC, 16.0f));
            }

        // O += P @ V : f16 16x16x32; vf b128 at bank floor, read once per n
        #pragma unroll
        for (int n = 0; n < 16; ++n) {
            h8 vf = *(const h8_a*)&V_lds[b][n * 16 + l15][qq * 8];
            acc[0][n] = __builtin_amdgcn_mfma_f32_16x16x32_f16(pfrag[0], vf, acc[0][n], 0, 0, 0);
            acc[1][n] = __builtin_amdgcn_mfma_f32_16x16x32_f16(pfrag[1], vf, acc[1][n], 0, 0, 0);
        }
        accl[0] = __builtin_amdgcn_mfma_f32_16x16x32_f16(pfrag[0], of, accl[0], 0, 0, 0);
        accl[1] = __builtin_amdgcn_mfma_f32_16x16x32_f16(pfrag[1], of, accl[1], 0, 0, 0);

        // write tile it+1 into the other buffer; one barrier per iter
        if (it + 1 < ITERS) {
            int nb = b ^ 1;
            *(i32x4_a*)&K_lds[nb][kr][kc]      = kreg[0];
            *(i32x4_a*)&K_lds[nb][kr + 16][kc] = kreg[1];
            #pragma unroll
            for (int p = 0; p < 4; ++p) *(h8_a*)&V_lds[nb][vr + p * 64][vc] = vreg[p];
            __syncthreads();
        }
    }

    // epilogue: f16 O partials + fp32 l partials
    #pragma unroll
    for (int t = 0; t < 2; ++t) {
        #pragma unroll
        for (int n = 0; n < 16; ++n)
            #pragma unroll
            for (int r = 0; r < 4; ++r) {
                int row = qrow0 + t * 16 + qq * 4 + r;
                Op[((size_t)sp * SEQ + row) * DIM + n * 16 + l15] = (_Float16)acc[t][n][r];
            }
        if (l15 == 0) {
            #pragma unroll
            for (int r = 0; r < 4; ++r)
                lp[(size_t)sp * SEQ + qrow0 + t * 16 + qq * 4 + r] = accl[t][r];
        }
    }
}

// ---------------- combine: out = sum_s(Op_s) / sum_s(lp_s) ----------------
__global__ void combine(const _Float16* __restrict__ Op, const float* __restrict__ lp,
                        float* __restrict__ out) {
    int idx = blockIdx.x * 256 + threadIdx.x;   // f32x4 chunk, 524288 total
    int row = idx >> 6;
    f32x4 a = {};
    float l = 0.0f;
    #pragma unroll
    for (int s = 0; s < NSPLIT; ++s) {
        h4 h = *(const h4*)(Op + (size_t)s * SEQ * DIM + (size_t)idx * 4);
        a.x += (float)h.x; a.y += (float)h.y; a.z += (float)h.z; a.w += (float)h.w;
        l += lp[s * SEQ + row];
    }
    float linv = 1.0f / (l + 1e-20f);
    ((f32x4*)out)[idx] = a * linv;
}

extern "C" void kernel_launch(void* const* d_in, const int* in_sizes, int n_in,
                              void* d_out, int out_size, void* d_ws, size_t ws_size,
                              hipStream_t stream) {
    const float* Q = (const float*)d_in[0];
    const float* K = (const float*)d_in[1];
    const float* V = (const float*)d_in[2];
    float* out = (float*)d_out;

    char* ws = (char*)d_ws;
    unsigned char* Q8 = (unsigned char*)ws;                // 2 MB fp8
    unsigned char* K8 = (unsigned char*)(ws + (2u << 20)); // 2 MB fp8
    _Float16* Vt = (_Float16*)(ws + (4u << 20));           // 4 MB f16 tiled-T (pi-permuted)
    _Float16* Op = (_Float16*)(ws + (8u << 20));           // 32 MB f16 partials
    float*    lp = (float*)(ws + (40u << 20));             // 256 KB

    prep   <<<256, 256, 0, stream>>>(Q, K, V, Q8, K8, Vt);
    attn   <<<NSPLIT * (SEQ / BM), 256, 0, stream>>>(Q8, K8, Vt, Op, lp);
    combine<<<2048, 256, 0, stream>>>(Op, lp, out);
}